// Round 1
// baseline (568.132 us; speedup 1.0000x reference)
//
#include <hip/hip_runtime.h>
#include <hip/hip_bf16.h>

// Monarch block-MLP fused, bf16 MFMA, fp32 accumulate.
//
// Semantics (verified against the JAX reference):
//   y0[b,kb,s] = sum_m x[b, kb*64+m] * w0[kb,m,s]              (kb in 64, s in 128)
//   z [b,s*64+j] = elu( sum_kb y0[b,kb,s] * w1[s,kb,j] + b1[s,j] )
//   y2[b,kb,s] = sum_m z[b, kb*64+m] * w2[kb,m,s]              (kb in 128, s in 64)
//   out[b,s*64+j] = sum_kb y2[b,kb,s] * w3[s,kb,j] + b3[s,j]
//
// Both halves share one template: fused_two_stage<KB, SN, STAGE1>.
// Per workgroup: M=32 rows, SC=16 s-chunk, 8 waves (512 thr), KG=32 k-blocks
// per group. Stage A MFMAs produce y0 fragments -> padded LDS -> stage B
// MFMAs accumulate K over groups. Weights are pre-cast/transposed to bf16 so
// every MFMA B-fragment is one contiguous 16B load.

typedef __attribute__((ext_vector_type(8))) short short8;
typedef __attribute__((ext_vector_type(4))) float floatx4;

__device__ __forceinline__ unsigned short f2bf(float f) {
    // round-to-nearest-even fp32 -> bf16 bits
    unsigned int u = __float_as_uint(f);
    unsigned int r = 0x7FFFu + ((u >> 16) & 1u);
    return (unsigned short)((u + r) >> 16);
}

// out[b][c][r] = bf16(in[b][r][c])   (batched 2D transpose + cast)
__global__ void transpose_cast_k(const float* __restrict__ in,
                                 unsigned short* __restrict__ out,
                                 int Bn, int R, int C) {
    int total = Bn * R * C;
    int stride = gridDim.x * blockDim.x;
    for (int idx = blockIdx.x * blockDim.x + threadIdx.x; idx < total; idx += stride) {
        int rc = R * C;
        int b = idx / rc;
        int rem = idx - b * rc;
        int c = rem / R;
        int r = rem - c * R;
        out[idx] = f2bf(in[(size_t)(b * R + r) * C + c]);
    }
}

// MFMA 16x16x32 bf16 fragment layouts (learn_hip m89-verified):
//   A: row = lane&15, k = (lane>>4)*8 + i   (8 contiguous bf16 per lane)
//   B: col = lane&15, k = (lane>>4)*8 + i
//   D: col = lane&15, row = (lane>>4)*4 + reg
template<int KB, int SN, bool STAGE1>
__global__ __launch_bounds__(512) void fused_two_stage(
    const float* __restrict__ xf,             // STAGE1 input (bs x KB*64) fp32
    const unsigned short* __restrict__ xb,    // !STAGE1 input bf16
    const unsigned short* __restrict__ wat,   // [KB][SN][64] bf16 (w0/w2 transposed)
    const unsigned short* __restrict__ wbt,   // [SN][64][KB] bf16 (w1/w3 transposed)
    const float* __restrict__ bias,           // [SN*64] f32
    unsigned short* __restrict__ ob,          // STAGE1 output z, bf16
    float* __restrict__ of)                   // !STAGE1 output, f32
{
    constexpr int KG = 32;            // k-blocks per group (stage-B MFMA K=32)
    constexpr int G  = KB / KG;
    constexpr int IW = KB * 64;       // input row width
    constexpr int OW = SN * 64;       // output row width

    const int tid  = threadIdx.x;
    const int lane = tid & 63;
    const int wave = tid >> 6;        // 0..7
    const int l15  = lane & 15;
    const int l4   = lane >> 4;       // 0..3
    const int rt   = wave >> 2;       // row half (16 rows each)
    const int wq   = wave & 3;        // stage A: kbl stripe; stage B: j-quarter
    const int r0   = blockIdx.x * 32;
    const int s0   = blockIdx.y * 16;

    // [r][s][kbl]; s-dim padded 16->17, kbl-dim 32->40 so that both the
    // D-layout scattered writes and the A-frag b128 reads land on ~2-way
    // bank aliasing (free) instead of 16-way conflicts.
    __shared__ __align__(16) unsigned short y0s[32][17][40];

    floatx4 accB[16];
#pragma unroll
    for (int s = 0; s < 16; ++s) accB[s] = (floatx4){0.f, 0.f, 0.f, 0.f};

    const int arow = r0 + rt * 16 + l15;

    for (int g = 0; g < G; ++g) {
        // ---- stage A: y0[r, kbl, s] for this group's 32 k-blocks ----
#pragma unroll
        for (int t = 0; t < 8; ++t) {
            const int kbl = wq + 4 * t;
            const int kb  = g * KG + kbl;
            floatx4 acc0 = (floatx4){0.f, 0.f, 0.f, 0.f};
#pragma unroll
            for (int ks = 0; ks < 2; ++ks) {
                const int m0 = kb * 64 + ks * 32 + l4 * 8;
                short8 afrag;
                if constexpr (STAGE1) {
                    const float* p = xf + (size_t)arow * IW + m0;
                    floatx4 f0 = *reinterpret_cast<const floatx4*>(p);
                    floatx4 f1 = *reinterpret_cast<const floatx4*>(p + 4);
#pragma unroll
                    for (int i = 0; i < 4; ++i) {
                        afrag[i]     = (short)f2bf(f0[i]);
                        afrag[i + 4] = (short)f2bf(f1[i]);
                    }
                } else {
                    afrag = *reinterpret_cast<const short8*>(xb + (size_t)arow * IW + m0);
                }
                const short8 bfrag = *reinterpret_cast<const short8*>(
                    wat + ((size_t)kb * SN + s0 + l15) * 64 + ks * 32 + l4 * 8);
                acc0 = __builtin_amdgcn_mfma_f32_16x16x32_bf16(afrag, bfrag, acc0, 0, 0, 0);
            }
            // D: col(=s) = l15, row = l4*4+rg  -> y0s[row][s][kbl]
#pragma unroll
            for (int rg = 0; rg < 4; ++rg)
                y0s[rt * 16 + l4 * 4 + rg][l15][kbl] = f2bf(acc0[rg]);
        }
        __syncthreads();

        // ---- stage B: acc[s] (16 rows x 16 j) += y0 (Mx32) @ wb (32x64) ----
#pragma unroll
        for (int s = 0; s < 16; ++s) {
            const short8 af = *reinterpret_cast<const short8*>(&y0s[rt * 16 + l15][s][l4 * 8]);
            const short8 bf = *reinterpret_cast<const short8*>(
                wbt + ((size_t)(s0 + s) * 64 + wq * 16 + l15) * KB + g * KG + l4 * 8);
            accB[s] = __builtin_amdgcn_mfma_f32_16x16x32_bf16(af, bf, accB[s], 0, 0, 0);
        }
        __syncthreads();
    }

    // ---- epilogue: bias (+ELU) and store ----
#pragma unroll
    for (int s = 0; s < 16; ++s) {
        const int col = (s0 + s) * 64 + wq * 16 + l15;
        const float bv = bias[col];
#pragma unroll
        for (int rg = 0; rg < 4; ++rg) {
            const int row = r0 + rt * 16 + l4 * 4 + rg;
            float v = accB[s][rg] + bv;
            if constexpr (STAGE1) {
                v = v > 0.f ? v : expm1f(v);
                ob[(size_t)row * OW + col] = f2bf(v);
            } else {
                of[(size_t)row * OW + col] = v;
            }
        }
    }
}

extern "C" void kernel_launch(void* const* d_in, const int* in_sizes, int n_in,
                              void* d_out, int out_size, void* d_ws, size_t ws_size,
                              hipStream_t stream) {
    const float* x  = (const float*)d_in[0];
    const float* w0 = (const float*)d_in[1];
    const float* w1 = (const float*)d_in[2];
    const float* b1 = (const float*)d_in[3];
    const float* w2 = (const float*)d_in[4];
    const float* w3 = (const float*)d_in[5];
    const float* b3 = (const float*)d_in[6];
    float* out = (float*)d_out;

    const int bs = in_sizes[0] / 4096;      // 8192

    // workspace layout (bf16): z[bs*8192] | w0t | w1t | w2t | w3t (1 MiB each)
    unsigned short* z   = (unsigned short*)d_ws;
    const size_t zElems = (size_t)bs * 8192;
    unsigned short* w0t = z + zElems;                 // [64][128][64]
    unsigned short* w1t = w0t + 64 * 128 * 64;        // [128][64][64]
    unsigned short* w2t = w1t + 128 * 64 * 64;        // [128][64][64]
    unsigned short* w3t = w2t + 128 * 64 * 64;        // [64][64][128]
    const size_t needed = (zElems + 4ull * 524288) * sizeof(unsigned short);
    if (n_in < 7 || (bs & 31) || ws_size < needed) return;  // clean failure signal

    // weight pre-transpose + bf16 cast (4 MiB total; L2-resident afterwards)
    transpose_cast_k<<<dim3(512), dim3(256), 0, stream>>>(w0, w0t, 64, 64, 128);
    transpose_cast_k<<<dim3(512), dim3(256), 0, stream>>>(w1, w1t, 128, 64, 64);
    transpose_cast_k<<<dim3(512), dim3(256), 0, stream>>>(w2, w2t, 128, 64, 64);
    transpose_cast_k<<<dim3(512), dim3(256), 0, stream>>>(w3, w3t, 64, 128, 64);

    // K1: x (fp32) -> z (bf16), with bias b1 + ELU
    fused_two_stage<64, 128, true><<<dim3(bs / 32, 8), dim3(512), 0, stream>>>(
        x, nullptr, w0t, w1t, b1, z, nullptr);
    // K2: z (bf16) -> out (fp32), with bias b3
    fused_two_stage<128, 64, false><<<dim3(bs / 32, 4), dim3(512), 0, stream>>>(
        nullptr, z, w2t, w3t, b3, nullptr, out);
}